// Round 5
// baseline (1996.190 us; speedup 1.0000x reference)
//
#include <hip/hip_runtime.h>

// ---------------------------------------------------------------------------
// Bidirectional 2-layer GRU (B=256, T=256, H=256, IN0=4) + head.  v5.
//
// v1: Whh streamed from L2 each step -> per-CU L2-port bound.
// v2: cross-WG h exchange via global -> XCD-coherence disaster.
// v3: 8-wave WG, ~300 VGPR demand vs 256 cap -> compiler re-streamed (128).
// v4: 8-wave, demand ~250 vs 256 cap -> compiler STILL re-streamed (120),
//     only the LDS-resident kk6..7 slices stuck -> 663 us/pass.
// v5: 4-wave WG (1 wave/SIMD => 512-VGPR budget). Per wave 12 N-tiles:
//     kk0..5 in regs (288 VGPR, asm-pinned against remat), kk6..7 in LDS
//     (96 KB), ext frags in regs (64). Demand ~470 <= 512.
//     ROWS=8 batch rows per WG (L0: 64 WGs, L1: 32 WGs) to cut per-SIMD
//     VALU work and spread L1's xp streaming.
//
// Workspace (bytes):
//   0          whhf  : 3*48*8*64*16  = 1,179,648
//   1179648    wextf : 3*4*16*64*16  =   196,608
//   1376256    w1b   : 768*512*2     =   786,432
//   2162688    h0c   : 65536*512*2   = 67,108,864  rows b*256+t, 512 cols
//   69271552   xp1g  : [t][b][768]*2 = 100,663,296
//   169934848  hb255 : 256*256*4     =   262,144
//   170196992  hfl   : 256*256*4     =   262,144
// ---------------------------------------------------------------------------

typedef __attribute__((ext_vector_type(8))) short short8;
typedef __attribute__((ext_vector_type(4))) float f32x4;

__device__ __forceinline__ short f2bf(float f) {
  union { float f; unsigned u; } v; v.f = f;
  unsigned r = v.u + 0x7fffu + ((v.u >> 16) & 1u);
  return (short)(r >> 16);
}
__device__ __forceinline__ float bf2f(unsigned short b) {
  union { unsigned u; float f; } v; v.u = ((unsigned)b) << 16; return v.f;
}
__device__ __forceinline__ float sigf(float x) {
  return __builtin_amdgcn_rcpf(1.f + __expf(-x));
}
__device__ __forceinline__ float tanhf_(float x) {
  return 1.f - 2.f * __builtin_amdgcn_rcpf(1.f + __expf(2.f * x));
}
__device__ __forceinline__ void gload_lds16(const void* g, void* s) {
  __builtin_amdgcn_global_load_lds(
      (const __attribute__((address_space(1))) unsigned int*)g,
      (__attribute__((address_space(3))) unsigned int*)s, 16, 0, 0);
}
#define US4_GET(v, i) ((i) == 0 ? (v).x : (i) == 1 ? (v).y : (i) == 2 ? (v).z : (v).w)

// --------------------------- prep kernels ----------------------------------
// whhf[mat][nt48][kk8][lane][8] : W[mat](row=nt*16+l15, k=kk*32+lhi*8+s)
// wextf[mat][grp4][tt16][lane][8] : ext column frags, c = lhi*8+s
//   grp0 r : c<4 Wih0_r ; c==4 bih0+bhh0       (m<2)
//   grp1 z : likewise                          (m<2)
//   grp2 nh: c==4 bhh_n (m<2: bhh0; m==2: bhh1)
//   grp3 nx: c<4 Wih0_n ; c==4 bih0_n          (m<2)
__global__ __launch_bounds__(256) void prep_wf(
    const float* __restrict__ whh0, const float* __restrict__ whh1,
    const float* __restrict__ wih0, const float* __restrict__ bih0,
    const float* __restrict__ bhh0, const float* __restrict__ bhh1,
    short* __restrict__ whhf, short* __restrict__ wextf) {
  int tid = blockIdx.x * 256 + threadIdx.x;
  if (tid < 73728) {
    int l = tid & 63;
    int rest = tid >> 6;
    int kk = rest & 7;
    int rest2 = rest >> 3;
    int nt = rest2 % 48;
    int m  = rest2 / 48;
    int row = nt * 16 + (l & 15);
    int k0  = kk * 32 + (l >> 4) * 8;
    const float* src = (m < 2) ? (whh0 + (size_t)m * 768 * 256) : whh1;
    const float* p = src + (size_t)row * 256 + k0;
    short8 o;
    #pragma unroll
    for (int s = 0; s < 8; ++s) o[s] = f2bf(p[s]);
    ((short8*)whhf)[tid] = o;
  } else {
    int j = tid - 73728;
    int l = j & 63;
    int tt = (j >> 6) & 15;
    int grp = (j >> 10) & 3;
    int m = j >> 12;
    int l15 = l & 15, lhi = l >> 4;
    int gate = (grp <= 1) ? grp : 2;
    int row = gate * 256 + tt * 16 + l15;
    short8 o = {};
    #pragma unroll
    for (int s = 0; s < 8; ++s) {
      int c = lhi * 8 + s;
      float v = 0.f;
      if (grp == 2) {
        if (c == 4) v = (m < 2) ? bhh0[m * 768 + row] : bhh1[row];
      } else if (m < 2) {
        if (c < 4) v = wih0[((size_t)m * 768 + row) * 4 + c];
        else if (c == 4) {
          v = bih0[m * 768 + row];
          if (grp < 2) v += bhh0[m * 768 + row];
        }
      }
      o[s] = f2bf(v);
    }
    ((short8*)wextf)[j] = o;
  }
}

__global__ __launch_bounds__(256) void prep_w1b(const float* __restrict__ wih1,
                                                short* __restrict__ out) {
  int i = blockIdx.x * 256 + threadIdx.x;
  const float* p = wih1 + (size_t)i * 8;
  short8 o;
  #pragma unroll
  for (int s = 0; s < 8; ++s) o[s] = f2bf(p[s]);
  ((short8*)out)[i] = o;
}

// --------------------------- recurrence ------------------------------------
// 4 waves (1/SIMD), ROWS=8 batch rows, full 768 gate rows per WG.
// Wave w owns hidden cols [64w,64w+64): tiles g*16 + 4w + j (j=0..3).
// Whh kk0..5 in regs (pinned), kk6..7 in LDS. h panel swizzled LDS dbuf.
template <int LAYER>
__global__ __launch_bounds__(256, 1) void gru_step(
    const float* __restrict__ x,        // L0 [256][256][4]
    const short* __restrict__ wf,       // whhf (wextf at +589824 shorts)
    const unsigned short* __restrict__ xp1g, // L1 [t][b][768]
    short* __restrict__ h0c,            // L0 out: rows b*256+t, 512 cols
    float* __restrict__ hfl) {          // L1 out [b][256]
  constexpr int ROWS = 8;
  const int wg  = blockIdx.x;
  const int dir = (LAYER == 0) ? (wg >> 5) : 0;
  const int bt  = (LAYER == 0) ? (wg & 31) : wg;
  const int b0  = bt * ROWS;
  const int tid = threadIdx.x;
  const int w = tid >> 6, l = tid & 63, l15 = l & 15, lhi = l >> 4;
  const int mat = (LAYER == 0) ? dir : 2;
  const short* wext = wf + 589824;

  __shared__ __align__(16) short wlds[49152];   // 96 KB: kk6..7 x 48 tiles
  __shared__ __align__(16) short hb[2][4096];   // 16 KB (rows >= ROWS stay 0)
  __shared__ __align__(16) short ext2[2][640];  // L0 x-ext (rows >= ROWS = 0)

  // ---- stage kk6..7 into LDS: 96 blocks of 1KB, wave-uniform dest ----
  #pragma unroll
  for (int r = 0; r < 24; ++r) {
    const int Bb = r * 4 + w;                    // 0..95: tile=Bb>>1, kkl=Bb&1
    gload_lds16(wf + ((size_t)(mat * 48 + (Bb >> 1)) * 8 + 6 + (Bb & 1)) * 512 + l * 8,
                &wlds[Bb * 512]);
  }
  for (int i = tid; i < 8192; i += 256) ((short*)hb)[i] = 0;
  for (int i = tid; i < 1280; i += 256) ((short*)ext2)[i] = 0;

  // ---- persistent regs: Whh kk0..5 (72 frags) + ext (16 frags) ----
  short8 wreg[3][4][6];
  #pragma unroll
  for (int g = 0; g < 3; ++g)
    #pragma unroll
    for (int j = 0; j < 4; ++j) {
      const int tile = g * 16 + 4 * w + j;
      #pragma unroll
      for (int kk = 0; kk < 6; ++kk)
        wreg[g][j][kk] = ((const short8*)wf)[((size_t)(mat * 48 + tile) * 8 + kk) * 64 + l];
    }
  short8 aext[4][4];
  #pragma unroll
  for (int grp = 0; grp < 4; ++grp)
    #pragma unroll
    for (int j = 0; j < 4; ++j) {
      if (LAYER == 1 && grp != 2) continue;
      aext[grp][j] = ((const short8*)wext)[((size_t)(mat * 4 + grp) * 16 + 4 * w + j) * 64 + l];
    }
  // pin against rematerialization (opaque defs; allocator must keep live)
  #pragma unroll
  for (int g = 0; g < 3; ++g)
    #pragma unroll
    for (int j = 0; j < 4; ++j)
      #pragma unroll
      for (int kk = 0; kk < 6; ++kk)
        asm volatile("" : "+v"(wreg[g][j][kk]));
  #pragma unroll
  for (int grp = 0; grp < 4; ++grp)
    #pragma unroll
    for (int j = 0; j < 4; ++j) {
      if (LAYER == 1 && grp != 2) continue;
      asm volatile("" : "+v"(aext[grp][j]));
    }

  __syncthreads();
  if (LAYER == 0 && tid < ROWS) {
    const int t0 = dir ? 255 : 0;
    float4 xe = ((const float4*)x)[(size_t)(b0 + tid) * 256 + t0];
    short8 e = {};
    e[0] = f2bf(xe.x); e[1] = f2bf(xe.y); e[2] = f2bf(xe.z); e[3] = f2bf(xe.w);
    e[4] = (short)0x3F80;
    *(short8*)&ext2[0][tid * 40] = e;
  }
  float hreg[4][4] = {};
  __syncthreads();

  for (int t = 0; t < 256; ++t) {
    const int cur = t & 1;

    // ---- prefetch x_{t+1} -> ext2[cur^1] (L0) ----
    if (LAYER == 0 && tid < ROWS && t < 255) {
      const int tn = dir ? 254 - t : t + 1;
      float4 xe = ((const float4*)x)[(size_t)(b0 + tid) * 256 + tn];
      short8 e = {};
      e[0] = f2bf(xe.x); e[1] = f2bf(xe.y); e[2] = f2bf(xe.z); e[3] = f2bf(xe.w);
      e[4] = (short)0x3F80;
      *(short8*)&ext2[cur ^ 1][tid * 40] = e;
    }

    // ---- L1: xp loads (12 x ushort4 per lane) ----
    ushort4 xq[3][4];
    if (LAYER == 1) {
      const unsigned short* base = xp1g + ((size_t)t * 256 + (b0 + (l15 & 7))) * 768;
      #pragma unroll
      for (int g = 0; g < 3; ++g)
        #pragma unroll
        for (int j = 0; j < 4; ++j)
          xq[g][j] = *(const ushort4*)(base + g * 256 + 64 * w + 16 * j + lhi * 4);
    }

    // ---- h0c writeback of h_{t-1} (L0): 8 rows x 512B = 256 granules ----
    if (LAYER == 0 && t > 0) {
      const int tprev = dir ? 256 - t : t - 1;
      const int br = tid >> 5, c = tid & 31;
      short8 v = *(const short8*)&hb[cur][br * 256 + ((c ^ (br & 7)) << 3)];
      __builtin_nontemporal_store(v,
          (short8*)(h0c + ((size_t)(b0 + br) * 256 + tprev) * 512 + dir * 256 + c * 8));
    }

    // ---- gates GEMM: kk0..5 regs, kk6..7 LDS ----
    f32x4 acc[3][4] = {};
    f32x4 accx[4] = {};
    #pragma unroll
    for (int kk = 0; kk < 8; ++kk) {
      const int gidx = kk * 4 + lhi;
      const short8 bfr = *(const short8*)&hb[cur][l15 * 256 + ((gidx ^ (l15 & 7)) << 3)];
      if (kk < 6) {
        #pragma unroll
        for (int g = 0; g < 3; ++g)
          #pragma unroll
          for (int j = 0; j < 4; ++j)
            acc[g][j] = __builtin_amdgcn_mfma_f32_16x16x32_bf16(wreg[g][j][kk], bfr, acc[g][j], 0, 0, 0);
      } else {
        #pragma unroll
        for (int g = 0; g < 3; ++g)
          #pragma unroll
          for (int j = 0; j < 4; ++j) {
            const int tile = g * 16 + 4 * w + j;
            const short8 wl = *(const short8*)&wlds[(tile * 2 + (kk - 6)) * 512 + l * 8];
            acc[g][j] = __builtin_amdgcn_mfma_f32_16x16x32_bf16(wl, bfr, acc[g][j], 0, 0, 0);
          }
      }
    }
    // ---- ext column ----
    if (LAYER == 0) {
      const short8 bext = *(const short8*)&ext2[cur][l15 * 40 + lhi * 8];
      #pragma unroll
      for (int j = 0; j < 4; ++j) {
        acc[0][j] = __builtin_amdgcn_mfma_f32_16x16x32_bf16(aext[0][j], bext, acc[0][j], 0, 0, 0);
        acc[1][j] = __builtin_amdgcn_mfma_f32_16x16x32_bf16(aext[1][j], bext, acc[1][j], 0, 0, 0);
        acc[2][j] = __builtin_amdgcn_mfma_f32_16x16x32_bf16(aext[2][j], bext, acc[2][j], 0, 0, 0);
        accx[j]   = __builtin_amdgcn_mfma_f32_16x16x32_bf16(aext[3][j], bext, accx[j], 0, 0, 0);
      }
    } else {
      short8 e = {};
      if (lhi == 0) e[4] = (short)0x3F80;
      #pragma unroll
      for (int j = 0; j < 4; ++j)
        acc[2][j] = __builtin_amdgcn_mfma_f32_16x16x32_bf16(aext[2][j], e, acc[2][j], 0, 0, 0);
    }

    // ---- elementwise GRU cell + write h_t -> hb[cur^1] ----
    #pragma unroll
    for (int j = 0; j < 4; ++j) {
      float hv[4];
      #pragma unroll
      for (int i = 0; i < 4; ++i) {
        float r, z, n;
        if (LAYER == 0) {
          r = sigf(acc[0][j][i]);
          z = sigf(acc[1][j][i]);
          n = tanhf_(accx[j][i] + r * acc[2][j][i]);
        } else {
          r = sigf(acc[0][j][i] + bf2f(US4_GET(xq[0][j], i)));
          z = sigf(acc[1][j][i] + bf2f(US4_GET(xq[1][j], i)));
          n = tanhf_(bf2f(US4_GET(xq[2][j], i)) + r * acc[2][j][i]);
        }
        const float h = n + z * (hreg[j][i] - n);
        hreg[j][i] = h;
        hv[i] = h;
      }
      if (l15 < ROWS) {
        const int gsw = 8 * w + 2 * j + (lhi >> 1);
        const int so = l15 * 256 + ((gsw ^ (l15 & 7)) << 3) + (lhi & 1) * 4;
        unsigned p01 = (unsigned)(unsigned short)f2bf(hv[0]) |
                       ((unsigned)(unsigned short)f2bf(hv[1]) << 16);
        unsigned p23 = (unsigned)(unsigned short)f2bf(hv[2]) |
                       ((unsigned)(unsigned short)f2bf(hv[3]) << 16);
        uint2 pk; pk.x = p01; pk.y = p23;
        *(uint2*)&hb[cur ^ 1][so] = pk;
      }
    }
    __syncthreads();
  }

  // tail
  if (LAYER == 0) {
    const int tlast = dir ? 0 : 255;
    const int br = tid >> 5, c = tid & 31;
    short8 v = *(const short8*)&hb[0][br * 256 + ((c ^ (br & 7)) << 3)];
    __builtin_nontemporal_store(v,
        (short8*)(h0c + ((size_t)(b0 + br) * 256 + tlast) * 512 + dir * 256 + c * 8));
  } else if (l15 < ROWS) {
    #pragma unroll
    for (int j = 0; j < 4; ++j)
      #pragma unroll
      for (int i = 0; i < 4; ++i)
        hfl[(size_t)(b0 + l15) * 256 + 64 * w + 16 * j + lhi * 4 + i] = hreg[j][i];
  }
}

// --------------------------- xp1 GEMM --------------------------------------
__global__ __launch_bounds__(256, 2) void xp1_gemm(
    const short* __restrict__ h0c, const short* __restrict__ w1b,
    const float* __restrict__ bih1, const float* __restrict__ bhh1,
    unsigned short* __restrict__ xp1g) {
  const int mb = blockIdx.x, nb = blockIdx.y;
  const int tid = threadIdx.x;
  const int w = tid >> 6, l = tid & 63, l15 = l & 15, lhi = l >> 4;
  const int wm = w >> 1, wn = w & 1;
  __shared__ __align__(16) short As[128 * 64];
  __shared__ __align__(16) short Bs[128 * 64];
  f32x4 acc[4][4] = {};

  for (int ks = 0; ks < 8; ++ks) {
    short8 sa[4], sb[4];
    #pragma unroll
    for (int c = 0; c < 4; ++c) {
      int li = w * 256 + c * 64 + l;
      int row = li >> 3, cgr = li & 7;
      sa[c] = *(const short8*)(h0c + (size_t)(mb * 128 + row) * 512 + ks * 64 + cgr * 8);
      sb[c] = *(const short8*)(w1b + (size_t)(nb * 128 + row) * 512 + ks * 64 + cgr * 8);
    }
    __syncthreads();
    #pragma unroll
    for (int c = 0; c < 4; ++c) {
      int li = w * 256 + c * 64 + l;
      int row = li >> 3, cgr = li & 7;
      int sl = ((cgr ^ (row & 7)) << 3);
      *(short8*)&As[row * 64 + sl] = sa[c];
      *(short8*)&Bs[row * 64 + sl] = sb[c];
    }
    __syncthreads();
    short8 af[4][2], bfr[4][2];
    #pragma unroll
    for (int mt = 0; mt < 4; ++mt)
      #pragma unroll
      for (int kk = 0; kk < 2; ++kk) {
        int row = wm * 64 + mt * 16 + l15;
        int g = kk * 4 + lhi;
        af[mt][kk] = *(const short8*)&As[row * 64 + ((g ^ (row & 7)) << 3)];
      }
    #pragma unroll
    for (int nt2 = 0; nt2 < 4; ++nt2)
      #pragma unroll
      for (int kk = 0; kk < 2; ++kk) {
        int row = wn * 64 + nt2 * 16 + l15;
        int g = kk * 4 + lhi;
        bfr[nt2][kk] = *(const short8*)&Bs[row * 64 + ((g ^ (row & 7)) << 3)];
      }
    #pragma unroll
    for (int kk = 0; kk < 2; ++kk)
      #pragma unroll
      for (int mt = 0; mt < 4; ++mt)
        #pragma unroll
        for (int nt2 = 0; nt2 < 4; ++nt2)
          acc[mt][nt2] = __builtin_amdgcn_mfma_f32_16x16x32_bf16(
              af[mt][kk], bfr[nt2][kk], acc[mt][nt2], 0, 0, 0);
  }

  #pragma unroll
  for (int nt2 = 0; nt2 < 4; ++nt2) {
    const int gate = nb * 128 + wn * 64 + nt2 * 16 + l15;
    const float bias = bih1[gate] + ((gate < 512) ? bhh1[gate] : 0.f);
    #pragma unroll
    for (int mt = 0; mt < 4; ++mt)
      #pragma unroll
      for (int i = 0; i < 4; ++i) {
        const int rt = mb * 128 + wm * 64 + mt * 16 + lhi * 4 + i;
        const int b = rt >> 8, tt = rt & 255;
        xp1g[((size_t)tt * 256 + b) * 768 + gate] =
            (unsigned short)f2bf(acc[mt][nt2][i] + bias);
      }
  }
}

// --------------------------- layer-1 bwd single step -----------------------
__global__ __launch_bounds__(256) void bwd255(
    const short* __restrict__ h0c, const float* __restrict__ wih1,
    const float* __restrict__ bih1, const float* __restrict__ bhh1,
    float* __restrict__ hb) {
  const int b = blockIdx.x, j = threadIdx.x;
  __shared__ __align__(16) float hrow[512];
  const unsigned short* hr = (const unsigned short*)(h0c + (size_t)(b * 256 + 255) * 512);
  for (int k = j; k < 512; k += 256) hrow[k] = bf2f(hr[k]);
  __syncthreads();
  const float4* hr4 = (const float4*)hrow;
  float g[3];
  #pragma unroll
  for (int gi = 0; gi < 3; ++gi) {
    const float4* wr = (const float4*)(wih1 + (size_t)768 * 512 + (size_t)(gi * 256 + j) * 512);
    float s = 0.f;
    #pragma unroll 4
    for (int k = 0; k < 128; ++k) {
      float4 aq = hr4[k], bq = wr[k];
      s += aq.x * bq.x + aq.y * bq.y + aq.z * bq.z + aq.w * bq.w;
    }
    g[gi] = s + bih1[768 + gi * 256 + j];
  }
  float r = sigf(g[0] + bhh1[768 + j]);
  float z = sigf(g[1] + bhh1[768 + 256 + j]);
  float n = tanhf_(g[2] + r * bhh1[768 + 512 + j]);
  hb[b * 256 + j] = (1.f - z) * n;
}

// --------------------------- head ------------------------------------------
__global__ __launch_bounds__(64) void head(
    const float* __restrict__ hf, const float* __restrict__ hb,
    const float* __restrict__ wout, const float* __restrict__ bout,
    float* __restrict__ out) {
  const int b = blockIdx.x, l = threadIdx.x;
  float s0 = 0.f, s1 = 0.f, s2 = 0.f;
  for (int k = l; k < 256; k += 64) {
    float v = hf[b * 256 + k] + hb[b * 256 + k];
    s0 += v * wout[k];
    s1 += v * wout[256 + k];
    s2 += v * wout[512 + k];
  }
  #pragma unroll
  for (int off = 32; off > 0; off >>= 1) {
    s0 += __shfl_down(s0, off);
    s1 += __shfl_down(s1, off);
    s2 += __shfl_down(s2, off);
  }
  if (l == 0) {
    s0 += bout[0]; s1 += bout[1]; s2 += bout[2];
    float m = fmaxf(s0, fmaxf(s1, s2));
    float e0 = __expf(s0 - m), e1 = __expf(s1 - m), e2 = __expf(s2 - m);
    float inv = 1.f / (e0 + e1 + e2);
    out[b * 3 + 0] = e0 * inv;
    out[b * 3 + 1] = e1 * inv;
    out[b * 3 + 2] = e2 * inv;
  }
}

// --------------------------- launch ----------------------------------------
extern "C" void kernel_launch(void* const* d_in, const int* in_sizes, int n_in,
                              void* d_out, int out_size, void* d_ws, size_t ws_size,
                              hipStream_t stream) {
  const float* x    = (const float*)d_in[0];
  const float* wih0 = (const float*)d_in[1];
  const float* whh0 = (const float*)d_in[2];
  const float* bih0 = (const float*)d_in[3];
  const float* bhh0 = (const float*)d_in[4];
  const float* wih1 = (const float*)d_in[5];
  const float* whh1 = (const float*)d_in[6];
  const float* bih1 = (const float*)d_in[7];
  const float* bhh1 = (const float*)d_in[8];
  const float* wout = (const float*)d_in[9];
  const float* bout = (const float*)d_in[10];
  float* out = (float*)d_out;

  char* ws = (char*)d_ws;
  short* whhf           = (short*)(ws + 0);
  short* wextf          = (short*)(ws + 1179648);
  short* w1b            = (short*)(ws + 1376256);
  short* h0c            = (short*)(ws + 2162688);
  unsigned short* xp1g  = (unsigned short*)(ws + 69271552);
  float* hb255          = (float*)(ws + 169934848);
  float* hfl            = (float*)(ws + 170196992);

  prep_wf<<<336, 256, 0, stream>>>(whh0, whh1, wih0, bih0, bhh0, bhh1, whhf, wextf);
  prep_w1b<<<192, 256, 0, stream>>>(wih1, w1b);
  gru_step<0><<<64, 256, 0, stream>>>(x, whhf, nullptr, h0c, nullptr);
  bwd255<<<256, 256, 0, stream>>>(h0c, wih1, bih1, bhh1, hb255);
  xp1_gemm<<<dim3(512, 6), 256, 0, stream>>>(h0c, w1b, bih1, bhh1, xp1g);
  gru_step<1><<<32, 256, 0, stream>>>(nullptr, whhf, xp1g, nullptr, hfl);
  head<<<256, 64, 0, stream>>>(hfl, hb255, wout, bout, out);
}

// Round 10
// 1728.348 us; speedup vs baseline: 1.1550x; 1.1550x over previous
//
#include <hip/hip_runtime.h>

// ---------------------------------------------------------------------------
// Bidirectional 2-layer GRU (B=256, T=256, H=256, IN0=4) + head.  v6.
//
// v1: Whh streamed from L2 each step -> per-CU L2-port bound.
// v2: cross-WG h exchange via global -> XCD-coherence disaster.
// v3/v4: 8-wave WG: demand > 256/wave cap -> compiler re-streamed weights.
// v5: 4-wave + "+v" pins: arch-VGPR class caps at 256 (512 is VGPR+AGPR!)
//     -> 352 "+v"-pinned regs impossible -> split/respill; L1 scratch-spilled.
// v6: weights pinned into AGPRs ("+a" one-time volatile asm defs; MFMA reads
//     A directly from AGPR on gfx950). Per wave: kk0..3+ext in AGPR (256),
//     kk4 in VGPR (48), kk5..7 in LDS (144 KB). h panel [2][8][256] (8 KB),
//     x-ext column built in regs from predicated global load.
//
// Workspace (bytes):
//   0          whhf  : 3*48*8*64*16  = 1,179,648
//   1179648    wextf : 3*4*16*64*16  =   196,608
//   1376256    w1b   : 768*512*2     =   786,432
//   2162688    h0c   : 65536*512*2   = 67,108,864  rows b*256+t, 512 cols
//   69271552   xp1g  : [t][b][768]*2 = 100,663,296
//   169934848  hb255 : 256*256*4     =   262,144
//   170196992  hfl   : 256*256*4     =   262,144
// ---------------------------------------------------------------------------

typedef __attribute__((ext_vector_type(8))) short short8;
typedef __attribute__((ext_vector_type(4))) float f32x4;

__device__ __forceinline__ short f2bf(float f) {
  union { float f; unsigned u; } v; v.f = f;
  unsigned r = v.u + 0x7fffu + ((v.u >> 16) & 1u);
  return (short)(r >> 16);
}
__device__ __forceinline__ float bf2f(unsigned short b) {
  union { unsigned u; float f; } v; v.u = ((unsigned)b) << 16; return v.f;
}
__device__ __forceinline__ float sigf(float x) {
  return __builtin_amdgcn_rcpf(1.f + __expf(-x));
}
__device__ __forceinline__ float tanhf_(float x) {
  return 1.f - 2.f * __builtin_amdgcn_rcpf(1.f + __expf(2.f * x));
}
__device__ __forceinline__ void gload_lds16(const void* g, void* s) {
  __builtin_amdgcn_global_load_lds(
      (const __attribute__((address_space(1))) unsigned int*)g,
      (__attribute__((address_space(3))) unsigned int*)s, 16, 0, 0);
}
#define US4_GET(v, i) ((i) == 0 ? (v).x : (i) == 1 ? (v).y : (i) == 2 ? (v).z : (v).w)

// --------------------------- prep kernels ----------------------------------
// whhf[mat][nt48][kk8][lane][8] : W[mat](row=nt*16+l15, k=kk*32+lhi*8+s)
// wextf[mat][grp4][tt16][lane][8] : ext column frags, c = lhi*8+s
//   grp0 r : c<4 Wih0_r ; c==4 bih0+bhh0       (m<2)
//   grp1 z : likewise                          (m<2)
//   grp2 nh: c==4 bhh_n (m<2: bhh0; m==2: bhh1)
//   grp3 nx: c<4 Wih0_n ; c==4 bih0_n          (m<2)
__global__ __launch_bounds__(256) void prep_wf(
    const float* __restrict__ whh0, const float* __restrict__ whh1,
    const float* __restrict__ wih0, const float* __restrict__ bih0,
    const float* __restrict__ bhh0, const float* __restrict__ bhh1,
    short* __restrict__ whhf, short* __restrict__ wextf) {
  int tid = blockIdx.x * 256 + threadIdx.x;
  if (tid < 73728) {
    int l = tid & 63;
    int rest = tid >> 6;
    int kk = rest & 7;
    int rest2 = rest >> 3;
    int nt = rest2 % 48;
    int m  = rest2 / 48;
    int row = nt * 16 + (l & 15);
    int k0  = kk * 32 + (l >> 4) * 8;
    const float* src = (m < 2) ? (whh0 + (size_t)m * 768 * 256) : whh1;
    const float* p = src + (size_t)row * 256 + k0;
    short8 o;
    #pragma unroll
    for (int s = 0; s < 8; ++s) o[s] = f2bf(p[s]);
    ((short8*)whhf)[tid] = o;
  } else {
    int j = tid - 73728;
    int l = j & 63;
    int tt = (j >> 6) & 15;
    int grp = (j >> 10) & 3;
    int m = j >> 12;
    int l15 = l & 15, lhi = l >> 4;
    int gate = (grp <= 1) ? grp : 2;
    int row = gate * 256 + tt * 16 + l15;
    short8 o = {};
    #pragma unroll
    for (int s = 0; s < 8; ++s) {
      int c = lhi * 8 + s;
      float v = 0.f;
      if (grp == 2) {
        if (c == 4) v = (m < 2) ? bhh0[m * 768 + row] : bhh1[row];
      } else if (m < 2) {
        if (c < 4) v = wih0[((size_t)m * 768 + row) * 4 + c];
        else if (c == 4) {
          v = bih0[m * 768 + row];
          if (grp < 2) v += bhh0[m * 768 + row];
        }
      }
      o[s] = f2bf(v);
    }
    ((short8*)wextf)[j] = o;
  }
}

__global__ __launch_bounds__(256) void prep_w1b(const float* __restrict__ wih1,
                                                short* __restrict__ out) {
  int i = blockIdx.x * 256 + threadIdx.x;
  const float* p = wih1 + (size_t)i * 8;
  short8 o;
  #pragma unroll
  for (int s = 0; s < 8; ++s) o[s] = f2bf(p[s]);
  ((short8*)out)[i] = o;
}

// --------------------------- recurrence ------------------------------------
// 4 waves (1/SIMD), ROWS=8 batch rows. Wave w owns hidden cols [64w,64w+64):
// tiles g*16 + 4w + j. Whh kk0..3 (+ext) AGPR, kk4 VGPR, kk5..7 LDS.
// h panel [2][8][256] swizzled; MFMA B rows read row l15&7 (cols 8..15 unused).
template <int LAYER>
__global__ __launch_bounds__(256, 1) void gru_step(
    const float* __restrict__ x,        // L0 [256][256][4]
    const short* __restrict__ wf,       // whhf (wextf at +589824 shorts)
    const unsigned short* __restrict__ xp1g, // L1 [t][b][768]
    short* __restrict__ h0c,            // L0 out: rows b*256+t, 512 cols
    float* __restrict__ hfl,            // L1 out [b][256]
    const float* __restrict__ bhh1) {   // L1: [2][768]
  constexpr int ROWS = 8;
  const int wg  = blockIdx.x;
  const int dir = (LAYER == 0) ? (wg >> 5) : 0;
  const int bt  = (LAYER == 0) ? (wg & 31) : wg;
  const int b0  = bt * ROWS;
  const int tid = threadIdx.x;
  const int w = tid >> 6, l = tid & 63, l15 = l & 15, lhi = l >> 4;
  const int row8 = l15 & 7;
  const int mat = (LAYER == 0) ? dir : 2;
  const short* wext = wf + 589824;

  __shared__ __align__(16) short wlds[73728];   // 144 KB: [tile48][kkl3][512]
  __shared__ __align__(16) short hb[2][2048];   // 8 KB: [8][256]

  // ---- stage kk5..7 into LDS: 144 x 1KB blocks, wave-uniform dest ----
  #pragma unroll
  for (int r = 0; r < 36; ++r) {
    const int Bb = r * 4 + w;                   // 0..143
    const int tile = Bb / 3, kkl = Bb % 3;
    gload_lds16(wf + ((size_t)(mat * 48 + tile) * 8 + 5 + kkl) * 512 + l * 8,
                &wlds[Bb * 512]);
  }
  for (int i = tid; i < 4096; i += 256) ((short*)hb)[i] = 0;

  // ---- persistent weights: kk0..4 (60 frags) + ext (L0: 16 frags) ----
  short8 wreg[3][4][5];
  #pragma unroll
  for (int g = 0; g < 3; ++g)
    #pragma unroll
    for (int j = 0; j < 4; ++j) {
      const int tile = g * 16 + 4 * w + j;
      #pragma unroll
      for (int kk = 0; kk < 5; ++kk)
        wreg[g][j][kk] = ((const short8*)wf)[((size_t)(mat * 48 + tile) * 8 + kk) * 64 + l];
    }
  short8 aext[4][4];
  float bhhn[4][4];
  if (LAYER == 0) {
    #pragma unroll
    for (int grp = 0; grp < 4; ++grp)
      #pragma unroll
      for (int j = 0; j < 4; ++j)
        aext[grp][j] = ((const short8*)wext)[((size_t)(mat * 4 + grp) * 16 + 4 * w + j) * 64 + l];
  } else {
    #pragma unroll
    for (int j = 0; j < 4; ++j)
      #pragma unroll
      for (int i = 0; i < 4; ++i)
        bhhn[j][i] = bhh1[512 + 64 * w + 16 * j + lhi * 4 + i];
  }

  // ---- pins: one-time opaque (volatile) defs -> non-rematerializable ----
  // L0: AGPR = kk0..3 (48 frags, 192) + ext (16 frags, 64) = 256; kk4 VGPR.
  // L1: AGPR = kk0..4 (60 frags, 240); bhhn VGPR.
  #pragma unroll
  for (int g = 0; g < 3; ++g)
    #pragma unroll
    for (int j = 0; j < 4; ++j)
      #pragma unroll
      for (int kk = 0; kk < 5; ++kk) {
        if (LAYER == 0) {
          if (kk < 4) asm volatile("" : "+a"(wreg[g][j][kk]));
          else        asm volatile("" : "+v"(wreg[g][j][kk]));
        } else {
          asm volatile("" : "+a"(wreg[g][j][kk]));
        }
      }
  if (LAYER == 0) {
    #pragma unroll
    for (int grp = 0; grp < 4; ++grp)
      #pragma unroll
      for (int j = 0; j < 4; ++j)
        asm volatile("" : "+a"(aext[grp][j]));
  } else {
    #pragma unroll
    for (int j = 0; j < 4; ++j)
      #pragma unroll
      for (int i = 0; i < 4; ++i)
        asm volatile("" : "+v"(bhhn[j][i]));
  }

  float hreg[4][4] = {};
  __syncthreads();   // staging done (includes vmcnt drain)

  for (int t = 0; t < 256; ++t) {
    const int cur = t & 1;
    const int tact = (LAYER == 0 && dir == 1) ? (255 - t) : t;

    // ---- L0: x_t (predicated tiny load; consumed post-MFMA) ----
    float4 xe = {0.f, 0.f, 0.f, 0.f};
    if (LAYER == 0 && lhi == 0 && l15 < ROWS)
      xe = ((const float4*)x)[(size_t)(b0 + l15) * 256 + tact];

    // ---- L1: xp loads (12 x ushort4/lane; rows dup for l15>=8) ----
    ushort4 xq[3][4];
    if (LAYER == 1) {
      const unsigned short* base = xp1g + ((size_t)t * 256 + (b0 + row8)) * 768;
      #pragma unroll
      for (int g = 0; g < 3; ++g)
        #pragma unroll
        for (int j = 0; j < 4; ++j)
          xq[g][j] = *(const ushort4*)(base + g * 256 + 64 * w + 16 * j + lhi * 4);
    }

    // ---- h0c writeback of h_{t-1} (L0) ----
    if (LAYER == 0 && t > 0) {
      const int tprev = dir ? 256 - t : t - 1;
      const int br = tid >> 5, c = tid & 31;
      short8 v = *(const short8*)&hb[cur][br * 256 + ((c ^ br) << 3)];
      __builtin_nontemporal_store(v,
          (short8*)(h0c + ((size_t)(b0 + br) * 256 + tprev) * 512 + dir * 256 + c * 8));
    }

    // ---- gates GEMM: kk0..4 regs/AGPR, kk5..7 LDS ----
    f32x4 acc[3][4] = {};
    f32x4 accx[4] = {};
    #pragma unroll
    for (int kk = 0; kk < 8; ++kk) {
      const int gidx = kk * 4 + lhi;
      const short8 bfr = *(const short8*)&hb[cur][row8 * 256 + ((gidx ^ row8) << 3)];
      if (kk < 5) {
        #pragma unroll
        for (int g = 0; g < 3; ++g)
          #pragma unroll
          for (int j = 0; j < 4; ++j)
            acc[g][j] = __builtin_amdgcn_mfma_f32_16x16x32_bf16(wreg[g][j][kk], bfr, acc[g][j], 0, 0, 0);
      } else {
        #pragma unroll
        for (int g = 0; g < 3; ++g)
          #pragma unroll
          for (int j = 0; j < 4; ++j) {
            const int tile = g * 16 + 4 * w + j;
            const short8 wl = *(const short8*)&wlds[(tile * 3 + (kk - 5)) * 512 + l * 8];
            acc[g][j] = __builtin_amdgcn_mfma_f32_16x16x32_bf16(wl, bfr, acc[g][j], 0, 0, 0);
          }
      }
    }
    // ---- ext column (L0: input proj + biases via MFMA) ----
    if (LAYER == 0) {
      short8 bext = {};
      if (lhi == 0 && l15 < ROWS) {
        bext[0] = f2bf(xe.x); bext[1] = f2bf(xe.y);
        bext[2] = f2bf(xe.z); bext[3] = f2bf(xe.w);
        bext[4] = (short)0x3F80;
      }
      #pragma unroll
      for (int j = 0; j < 4; ++j) {
        acc[0][j] = __builtin_amdgcn_mfma_f32_16x16x32_bf16(aext[0][j], bext, acc[0][j], 0, 0, 0);
        acc[1][j] = __builtin_amdgcn_mfma_f32_16x16x32_bf16(aext[1][j], bext, acc[1][j], 0, 0, 0);
        acc[2][j] = __builtin_amdgcn_mfma_f32_16x16x32_bf16(aext[2][j], bext, acc[2][j], 0, 0, 0);
        accx[j]   = __builtin_amdgcn_mfma_f32_16x16x32_bf16(aext[3][j], bext, accx[j], 0, 0, 0);
      }
    }

    // ---- elementwise GRU cell + write h_t -> hb[cur^1] ----
    #pragma unroll
    for (int j = 0; j < 4; ++j) {
      float hv[4];
      #pragma unroll
      for (int i = 0; i < 4; ++i) {
        float r, z, n;
        if (LAYER == 0) {
          r = sigf(acc[0][j][i]);
          z = sigf(acc[1][j][i]);
          n = tanhf_(accx[j][i] + r * acc[2][j][i]);
        } else {
          r = sigf(acc[0][j][i] + bf2f(US4_GET(xq[0][j], i)));
          z = sigf(acc[1][j][i] + bf2f(US4_GET(xq[1][j], i)));
          n = tanhf_(bf2f(US4_GET(xq[2][j], i)) + r * (acc[2][j][i] + bhhn[j][i]));
        }
        const float h = n + z * (hreg[j][i] - n);
        hreg[j][i] = h;
        hv[i] = h;
      }
      if (l15 < ROWS) {
        const int gsw = 8 * w + 2 * j + (lhi >> 1);
        const int so = l15 * 256 + ((gsw ^ l15) << 3) + (lhi & 1) * 4;
        unsigned p01 = (unsigned)(unsigned short)f2bf(hv[0]) |
                       ((unsigned)(unsigned short)f2bf(hv[1]) << 16);
        unsigned p23 = (unsigned)(unsigned short)f2bf(hv[2]) |
                       ((unsigned)(unsigned short)f2bf(hv[3]) << 16);
        uint2 pk; pk.x = p01; pk.y = p23;
        *(uint2*)&hb[cur ^ 1][so] = pk;
      }
    }
    __syncthreads();
  }

  // tail: last h sits in hb[0] after t=255
  if (LAYER == 0) {
    const int tlast = dir ? 0 : 255;
    const int br = tid >> 5, c = tid & 31;
    short8 v = *(const short8*)&hb[0][br * 256 + ((c ^ br) << 3)];
    __builtin_nontemporal_store(v,
        (short8*)(h0c + ((size_t)(b0 + br) * 256 + tlast) * 512 + dir * 256 + c * 8));
  } else if (l15 < ROWS) {
    #pragma unroll
    for (int j = 0; j < 4; ++j)
      #pragma unroll
      for (int i = 0; i < 4; ++i)
        hfl[(size_t)(b0 + l15) * 256 + 64 * w + 16 * j + lhi * 4 + i] = hreg[j][i];
  }
}

// --------------------------- xp1 GEMM --------------------------------------
__global__ __launch_bounds__(256, 2) void xp1_gemm(
    const short* __restrict__ h0c, const short* __restrict__ w1b,
    const float* __restrict__ bih1, const float* __restrict__ bhh1,
    unsigned short* __restrict__ xp1g) {
  const int mb = blockIdx.x, nb = blockIdx.y;
  const int tid = threadIdx.x;
  const int w = tid >> 6, l = tid & 63, l15 = l & 15, lhi = l >> 4;
  const int wm = w >> 1, wn = w & 1;
  __shared__ __align__(16) short As[128 * 64];
  __shared__ __align__(16) short Bs[128 * 64];
  f32x4 acc[4][4] = {};

  for (int ks = 0; ks < 8; ++ks) {
    short8 sa[4], sb[4];
    #pragma unroll
    for (int c = 0; c < 4; ++c) {
      int li = w * 256 + c * 64 + l;
      int row = li >> 3, cgr = li & 7;
      sa[c] = *(const short8*)(h0c + (size_t)(mb * 128 + row) * 512 + ks * 64 + cgr * 8);
      sb[c] = *(const short8*)(w1b + (size_t)(nb * 128 + row) * 512 + ks * 64 + cgr * 8);
    }
    __syncthreads();
    #pragma unroll
    for (int c = 0; c < 4; ++c) {
      int li = w * 256 + c * 64 + l;
      int row = li >> 3, cgr = li & 7;
      int sl = ((cgr ^ (row & 7)) << 3);
      *(short8*)&As[row * 64 + sl] = sa[c];
      *(short8*)&Bs[row * 64 + sl] = sb[c];
    }
    __syncthreads();
    short8 af[4][2], bfr[4][2];
    #pragma unroll
    for (int mt = 0; mt < 4; ++mt)
      #pragma unroll
      for (int kk = 0; kk < 2; ++kk) {
        int row = wm * 64 + mt * 16 + l15;
        int g = kk * 4 + lhi;
        af[mt][kk] = *(const short8*)&As[row * 64 + ((g ^ (row & 7)) << 3)];
      }
    #pragma unroll
    for (int nt2 = 0; nt2 < 4; ++nt2)
      #pragma unroll
      for (int kk = 0; kk < 2; ++kk) {
        int row = wn * 64 + nt2 * 16 + l15;
        int g = kk * 4 + lhi;
        bfr[nt2][kk] = *(const short8*)&Bs[row * 64 + ((g ^ (row & 7)) << 3)];
      }
    #pragma unroll
    for (int kk = 0; kk < 2; ++kk)
      #pragma unroll
      for (int mt = 0; mt < 4; ++mt)
        #pragma unroll
        for (int nt2 = 0; nt2 < 4; ++nt2)
          acc[mt][nt2] = __builtin_amdgcn_mfma_f32_16x16x32_bf16(
              af[mt][kk], bfr[nt2][kk], acc[mt][nt2], 0, 0, 0);
  }

  #pragma unroll
  for (int nt2 = 0; nt2 < 4; ++nt2) {
    const int gate = nb * 128 + wn * 64 + nt2 * 16 + l15;
    const float bias = bih1[gate] + ((gate < 512) ? bhh1[gate] : 0.f);
    #pragma unroll
    for (int mt = 0; mt < 4; ++mt)
      #pragma unroll
      for (int i = 0; i < 4; ++i) {
        const int rt = mb * 128 + wm * 64 + mt * 16 + lhi * 4 + i;
        const int b = rt >> 8, tt = rt & 255;
        xp1g[((size_t)tt * 256 + b) * 768 + gate] =
            (unsigned short)f2bf(acc[mt][nt2][i] + bias);
      }
  }
}

// --------------------------- layer-1 bwd single step -----------------------
__global__ __launch_bounds__(256) void bwd255(
    const short* __restrict__ h0c, const float* __restrict__ wih1,
    const float* __restrict__ bih1, const float* __restrict__ bhh1,
    float* __restrict__ hb) {
  const int b = blockIdx.x, j = threadIdx.x;
  __shared__ __align__(16) float hrow[512];
  const unsigned short* hr = (const unsigned short*)(h0c + (size_t)(b * 256 + 255) * 512);
  for (int k = j; k < 512; k += 256) hrow[k] = bf2f(hr[k]);
  __syncthreads();
  const float4* hr4 = (const float4*)hrow;
  float g[3];
  #pragma unroll
  for (int gi = 0; gi < 3; ++gi) {
    const float4* wr = (const float4*)(wih1 + (size_t)768 * 512 + (size_t)(gi * 256 + j) * 512);
    float s = 0.f;
    #pragma unroll 4
    for (int k = 0; k < 128; ++k) {
      float4 aq = hr4[k], bq = wr[k];
      s += aq.x * bq.x + aq.y * bq.y + aq.z * bq.z + aq.w * bq.w;
    }
    g[gi] = s + bih1[768 + gi * 256 + j];
  }
  float r = sigf(g[0] + bhh1[768 + j]);
  float z = sigf(g[1] + bhh1[768 + 256 + j]);
  float n = tanhf_(g[2] + r * bhh1[768 + 512 + j]);
  hb[b * 256 + j] = (1.f - z) * n;
}

// --------------------------- head ------------------------------------------
__global__ __launch_bounds__(64) void head(
    const float* __restrict__ hf, const float* __restrict__ hb,
    const float* __restrict__ wout, const float* __restrict__ bout,
    float* __restrict__ out) {
  const int b = blockIdx.x, l = threadIdx.x;
  float s0 = 0.f, s1 = 0.f, s2 = 0.f;
  for (int k = l; k < 256; k += 64) {
    float v = hf[b * 256 + k] + hb[b * 256 + k];
    s0 += v * wout[k];
    s1 += v * wout[256 + k];
    s2 += v * wout[512 + k];
  }
  #pragma unroll
  for (int off = 32; off > 0; off >>= 1) {
    s0 += __shfl_down(s0, off);
    s1 += __shfl_down(s1, off);
    s2 += __shfl_down(s2, off);
  }
  if (l == 0) {
    s0 += bout[0]; s1 += bout[1]; s2 += bout[2];
    float m = fmaxf(s0, fmaxf(s1, s2));
    float e0 = __expf(s0 - m), e1 = __expf(s1 - m), e2 = __expf(s2 - m);
    float inv = 1.f / (e0 + e1 + e2);
    out[b * 3 + 0] = e0 * inv;
    out[b * 3 + 1] = e1 * inv;
    out[b * 3 + 2] = e2 * inv;
  }
}

// --------------------------- launch ----------------------------------------
extern "C" void kernel_launch(void* const* d_in, const int* in_sizes, int n_in,
                              void* d_out, int out_size, void* d_ws, size_t ws_size,
                              hipStream_t stream) {
  const float* x    = (const float*)d_in[0];
  const float* wih0 = (const float*)d_in[1];
  const float* whh0 = (const float*)d_in[2];
  const float* bih0 = (const float*)d_in[3];
  const float* bhh0 = (const float*)d_in[4];
  const float* wih1 = (const float*)d_in[5];
  const float* whh1 = (const float*)d_in[6];
  const float* bih1 = (const float*)d_in[7];
  const float* bhh1 = (const float*)d_in[8];
  const float* wout = (const float*)d_in[9];
  const float* bout = (const float*)d_in[10];
  float* out = (float*)d_out;

  char* ws = (char*)d_ws;
  short* whhf           = (short*)(ws + 0);
  short* wextf          = (short*)(ws + 1179648);
  short* w1b            = (short*)(ws + 1376256);
  short* h0c            = (short*)(ws + 2162688);
  unsigned short* xp1g  = (unsigned short*)(ws + 69271552);
  float* hb255          = (float*)(ws + 169934848);
  float* hfl            = (float*)(ws + 170196992);

  prep_wf<<<336, 256, 0, stream>>>(whh0, whh1, wih0, bih0, bhh0, bhh1, whhf, wextf);
  prep_w1b<<<192, 256, 0, stream>>>(wih1, w1b);
  gru_step<0><<<64, 256, 0, stream>>>(x, whhf, nullptr, h0c, nullptr, nullptr);
  bwd255<<<256, 256, 0, stream>>>(h0c, wih1, bih1, bhh1, hb255);
  xp1_gemm<<<dim3(512, 6), 256, 0, stream>>>(h0c, w1b, bih1, bhh1, xp1g);
  gru_step<1><<<32, 256, 0, stream>>>(nullptr, whhf, xp1g, nullptr, hfl, bhh1);
  head<<<256, 64, 0, stream>>>(hfl, hb255, wout, bout, out);
}